// Round 8
// baseline (253.038 us; speedup 1.0000x reference)
//
#include <hip/hip_runtime.h>
#include <hip/hip_fp16.h>
#include <cstdint>

typedef int v4i __attribute__((ext_vector_type(4)));

#define AS1C(p) ((const __attribute__((address_space(1))) void*)(p))
#define AS3(p)  ((__attribute__((address_space(3))) void*)(p))

// ---------------------------------------------------------------------------
// Fused per-row symmetric int8 quantization for BOTH activations and weights:
// one launch, 12288 blocks. Single pass — the 16 KB row lives in 16 VGPRs.
// ---------------------------------------------------------------------------
__global__ __launch_bounds__(256) void quant_fused(const float* __restrict__ X,
                                                   const float* __restrict__ W,
                                                   int8_t* __restrict__ Xq,
                                                   int8_t* __restrict__ Wq,
                                                   float* __restrict__ a_scale,
                                                   float* __restrict__ w_scale) {
    const int row = blockIdx.x;
    const float* src;
    int8_t* dst;
    float* scp;
    if (row < 8192) {
        src = X + (size_t)row * 4096;  dst = Xq + (size_t)row * 4096;  scp = a_scale + row;
    } else {
        const int r = row - 8192;
        src = W + (size_t)r * 4096;    dst = Wq + (size_t)r * 4096;    scp = w_scale + r;
    }
    const float4* xv = (const float4*)src;

    float4 v[4];
#pragma unroll
    for (int j = 0; j < 4; ++j) v[j] = xv[threadIdx.x + (j << 8)];

    float m = 0.0f;
#pragma unroll
    for (int j = 0; j < 4; ++j) {
        m = fmaxf(m, fmaxf(fmaxf(fabsf(v[j].x), fabsf(v[j].y)),
                           fmaxf(fabsf(v[j].z), fabsf(v[j].w))));
    }
    for (int off = 32; off > 0; off >>= 1)
        m = fmaxf(m, __shfl_xor(m, off, 64));

    __shared__ float wmax[4];
    __shared__ float s_sc;
    const int lane = threadIdx.x & 63;
    const int wv = threadIdx.x >> 6;
    if (lane == 0) wmax[wv] = m;
    __syncthreads();
    if (threadIdx.x == 0) {
        float mm = fmaxf(fmaxf(wmax[0], wmax[1]), fmaxf(wmax[2], wmax[3]));
        float sc = mm / 127.0f;
        *scp = sc;
        s_sc = sc;
    }
    __syncthreads();
    const float sc = s_sc;

    char4* qv = (char4*)dst;
#pragma unroll
    for (int j = 0; j < 4; ++j) {
        char4 q;
        q.x = (signed char)(int)rintf(v[j].x / sc);
        q.y = (signed char)(int)rintf(v[j].y / sc);
        q.z = (signed char)(int)rintf(v[j].z / sc);
        q.w = (signed char)(int)rintf(v[j].w / sc);
        qv[threadIdx.x + (j << 8)] = q;
    }
}

// ---------------------------------------------------------------------------
// int8 GEMM, 256x256 tile, 512 threads = 8 waves (2M x 4N), per-wave 128x64.
// NEW — B bypasses LDS: B fragments are loaded DIRECTLY global->VGPR, one
// tile ahead, double-buffered (4 x global_load_dwordx4 per wave per tile;
// B panels are L2-hot, reused by all 32 M-block rows). Only A is LDS-staged
// (ring of 4 x 16 KiB = 64 KiB). This cuts LDS-port demand per tile from
// ~1400 cyc (> MFMA's 1306 -> LDS-bound, the r3-r7 ~52% MfmaUtil wall) to
// ~900 cyc (64 A ds_read_b128 + 16 KB stage writes), making MFMA the
// binding resource with ~400 cyc slack. vmcnt(0) at each tile head is free:
// everything in flight is >=1 tile (~1400 cyc) old. All intra-tile
// sched_barrier fences removed (m141: order-pinning defeats the compiler's
// fine-grained lgkmcnt interleave of ds_read with MFMA).
// Ring audit: stage(kt+3) -> buf[(kt+3)&3], last read during tile kt-2
// (A-frags(kt-1)), two barriers earlier; writes land after head barrier of
// kt and are retired block-wide by vmcnt(0)+barrier at kt+2 before reads.
// ---------------------------------------------------------------------------
__global__ __launch_bounds__(512, 2) void gemm_i8(const int8_t* __restrict__ Aq,
                                                  const int8_t* __restrict__ Bq,
                                                  const float* __restrict__ a_scale,
                                                  const float* __restrict__ w_scale,
                                                  float* __restrict__ out) {
    extern __shared__ __align__(16) int8_t smem[];  // 4 x (A 16K)

    const int K = 4096;
    const int bid = blockIdx.x;
    const int wg  = (bid & 7) * 64 + (bid >> 3);  // bijective: 512 = 8 x 64
    const int n0 = (wg & 15) * 256;
    const int m0 = (wg >> 4) * 256;

    const int tid  = threadIdx.x;
    const int lane = tid & 63;
    const int wid  = tid >> 6;
    const int wm   = wid >> 2;
    const int wn   = wid & 3;

    // A fragment read offsets in LDS (64-B rows, 16-B-chunk XOR swizzle)
    const int rsel  = lane & 15;
    const int koff  = (lane >> 4) << 4;
    const int kswz  = koff ^ (((rsel >> 1) & 3) << 4);
    const int abase = (wm * 128 + rsel) * 64 + kswz;

    // B fragment global base: row = n0 + wn*64 + nt*16 + rsel, col = kt*64 + koff
    const int8_t* pB = Bq + (size_t)(n0 + wn * 64 + rsel) * K + koff;

    // A staging: 512 thr x 16 B = 8 KB/issue = 128 rows; pre-swizzled source
    const int strow = tid >> 2;
    const int stswz = ((strow >> 1) & 3) << 4;
    const int stcol = ((tid & 3) << 4) ^ stswz;
    const int8_t* gA = Aq + (size_t)(m0 + strow) * K + stcol;
    const size_t rstep = (size_t)128 * K;
    const int ldsst = wid * 1024;  // + lane*16 by HW

    v4i acc[8][4] = {};
    v4i aFa[8], aFb[8], bFa[4], bFb[4];

#define STAGE(buf, kt) do {                                                          \
    int8_t* _d = smem + (buf) * 16384;                                               \
    const int8_t* _a = gA + (size_t)(kt) * 64;                                       \
    __builtin_amdgcn_global_load_lds(AS1C(_a),         AS3(_d + ldsst),        16, 0, 0); \
    __builtin_amdgcn_global_load_lds(AS1C(_a + rstep), AS3(_d + 8192 + ldsst), 16, 0, 0); \
  } while (0)

#define KSTEP(u, CA, CB, NA, NB, kt4) do {                                           \
    const int kt  = (kt4) + (u);                                                     \
    const int8_t* bufN = smem + (((u) + 1) & 3) * 16384;                             \
    const int ktp = (kt + 3 < 64) ? (kt + 3) : 63;                                   \
    const int ktb = (kt + 1 < 64) ? (kt + 1) : 63;                                   \
    const int8_t* _pb = pB + (size_t)ktb * 64;                                       \
    asm volatile("s_waitcnt vmcnt(0)" ::: "memory");  /* all >=1-tile-old */         \
    __builtin_amdgcn_s_barrier();                                                    \
    STAGE(((u) + 3) & 3, ktp);                                                       \
    NB[0] = *(const v4i*)(_pb);                                                      \
    NB[1] = *(const v4i*)(_pb + (size_t)16 * K);                                     \
    NB[2] = *(const v4i*)(_pb + (size_t)32 * K);                                     \
    NB[3] = *(const v4i*)(_pb + (size_t)48 * K);                                     \
    _Pragma("unroll")                                                                \
    for (int g = 0; g < 4; ++g) {                                                    \
        NA[2*g]     = *(const v4i*)(bufN + abase + (2*g)     * 1024);                \
        NA[2*g + 1] = *(const v4i*)(bufN + abase + (2*g + 1) * 1024);                \
        __builtin_amdgcn_s_setprio(1);                                               \
        _Pragma("unroll")                                                            \
        for (int nt = 0; nt < 4; ++nt) {                                             \
            acc[2*g][nt] = __builtin_amdgcn_mfma_i32_16x16x64_i8(                    \
                CA[2*g], CB[nt], acc[2*g][nt], 0, 0, 0);                             \
            acc[2*g+1][nt] = __builtin_amdgcn_mfma_i32_16x16x64_i8(                  \
                CA[2*g+1], CB[nt], acc[2*g+1][nt], 0, 0, 0);                         \
        }                                                                            \
        __builtin_amdgcn_s_setprio(0);                                               \
    }                                                                                \
  } while (0)

    // ---- prologue: stage A tiles 0..2, load B(0) frags, retire, read A(0)
    STAGE(0, 0); STAGE(1, 1); STAGE(2, 2);
    bFa[0] = *(const v4i*)(pB);
    bFa[1] = *(const v4i*)(pB + (size_t)16 * K);
    bFa[2] = *(const v4i*)(pB + (size_t)32 * K);
    bFa[3] = *(const v4i*)(pB + (size_t)48 * K);
    asm volatile("s_waitcnt vmcnt(0)" ::: "memory");
    __builtin_amdgcn_s_barrier();
#pragma unroll
    for (int mt = 0; mt < 8; ++mt) aFa[mt] = *(const v4i*)(smem + abase + mt * 1024);

    for (int kt4 = 0; kt4 < 64; kt4 += 4) {
        KSTEP(0, aFa, bFa, aFb, bFb, kt4);
        KSTEP(1, aFb, bFb, aFa, bFa, kt4);
        KSTEP(2, aFa, bFa, aFb, bFb, kt4);
        KSTEP(3, aFb, bFb, aFa, bFa, kt4);
    }

    // epilogue: C/D layout col = lane&15 (N), row = (lane>>4)*4 + reg (M)
    const int r0  = (lane >> 4) << 2;
    const int col = lane & 15;
#pragma unroll
    for (int mt = 0; mt < 8; ++mt) {
        const int tbase = m0 + wm * 128 + mt * 16 + r0;
        float as[4];
#pragma unroll
        for (int r = 0; r < 4; ++r) as[r] = a_scale[tbase + r];
#pragma unroll
        for (int nt = 0; nt < 4; ++nt) {
            const int o = n0 + wn * 64 + nt * 16 + col;
            const float wsc = w_scale[o];
#pragma unroll
            for (int r = 0; r < 4; ++r) {
                float v = (float)acc[mt][nt][r] * as[r] * wsc;
                out[(size_t)(tbase + r) * 4096 + o] = __half2float(__float2half_rn(v));
            }
        }
    }
#undef KSTEP
#undef STAGE
}

extern "C" void kernel_launch(void* const* d_in, const int* in_sizes, int n_in,
                              void* d_out, int out_size, void* d_ws, size_t ws_size,
                              hipStream_t stream) {
    const float* input_act = (const float*)d_in[0];  // [4,2048,4096] = [8192,4096]
    const float* weight    = (const float*)d_in[1];  // [4096,4096]
    float* out = (float*)d_out;

    const int K = 4096, O = 4096, T = 8192;

    int8_t* x_q = (int8_t*)d_ws;
    int8_t* w_q = x_q + (size_t)T * K;
    float* a_scale = (float*)(w_q + (size_t)O * K);
    float* w_scale = a_scale + T;

    static bool attr_done = false;
    if (!attr_done) {
        hipFuncSetAttribute(reinterpret_cast<const void*>(gemm_i8),
                            hipFuncAttributeMaxDynamicSharedMemorySize, 65536);
        attr_done = true;
    }

    quant_fused<<<T + O, 256, 0, stream>>>(input_act, weight, x_q, w_q,
                                           a_scale, w_scale);

    dim3 grid(512);  // (8192/256) x (4096/256), XCD-swizzled in-kernel
    gemm_i8<<<grid, 512, 65536, stream>>>(x_q, w_q, a_scale, w_scale, out);
}

// Round 9
// 207.038 us; speedup vs baseline: 1.2222x; 1.2222x over previous
//
#include <hip/hip_runtime.h>
#include <hip/hip_fp16.h>
#include <cstdint>

typedef int v4i __attribute__((ext_vector_type(4)));

#define AS1C(p) ((const __attribute__((address_space(1))) void*)(p))
#define AS3(p)  ((__attribute__((address_space(3))) void*)(p))

// ---------------------------------------------------------------------------
// Fused per-row symmetric int8 quantization. Activations (rows 0..8191) are
// stored row-major. Weights (rows 8192..12287) are stored in MFMA-FRAGMENT
// layout: panel n16 = row/16 (64 KiB), K-tile kt (1 KiB), chunk
// l = ((k&63)>>4)<<4 | (row&15)  (16 B). GEMM lane l then loads its B
// fragment for (n16,kt) at base + l*16 — one fully-coalesced
// global_load_dwordx4 per fragment instead of a 16-line gather (the r8
// pathology). Store side scatters as 16-B segments at 256-B stride —
// absorbed by L2/L3 (w_q is 16 MiB, read back immediately by the GEMM).
// ---------------------------------------------------------------------------
__global__ __launch_bounds__(256) void quant_fused(const float* __restrict__ X,
                                                   const float* __restrict__ W,
                                                   int8_t* __restrict__ Xq,
                                                   int8_t* __restrict__ Wq,
                                                   float* __restrict__ a_scale,
                                                   float* __restrict__ w_scale) {
    const int row = blockIdx.x;
    const bool isW = row >= 8192;
    const int r = isW ? row - 8192 : row;
    const float* src = (isW ? W : X) + (size_t)r * 4096;
    float* scp = (isW ? w_scale : a_scale) + r;

    const float4* xv = (const float4*)src;
    const int tid = threadIdx.x;

    float4 v[4];
#pragma unroll
    for (int j = 0; j < 4; ++j) v[j] = xv[tid + (j << 8)];

    float m = 0.0f;
#pragma unroll
    for (int j = 0; j < 4; ++j) {
        m = fmaxf(m, fmaxf(fmaxf(fabsf(v[j].x), fabsf(v[j].y)),
                           fmaxf(fabsf(v[j].z), fabsf(v[j].w))));
    }
    for (int off = 32; off > 0; off >>= 1)
        m = fmaxf(m, __shfl_xor(m, off, 64));

    __shared__ float wmax[4];
    __shared__ float s_sc;
    const int lane = tid & 63;
    const int wv = tid >> 6;
    if (lane == 0) wmax[wv] = m;
    __syncthreads();
    if (tid == 0) {
        float mm = fmaxf(fmaxf(wmax[0], wmax[1]), fmaxf(wmax[2], wmax[3]));
        float sc = mm / 127.0f;
        *scp = sc;
        s_sc = sc;
    }
    __syncthreads();
    const float sc = s_sc;

    if (!isW) {
        char4* qv = (char4*)(Xq + (size_t)r * 4096);
#pragma unroll
        for (int j = 0; j < 4; ++j) {
            char4 q;
            q.x = (signed char)(int)rintf(v[j].x / sc);
            q.y = (signed char)(int)rintf(v[j].y / sc);
            q.z = (signed char)(int)rintf(v[j].z / sc);
            q.w = (signed char)(int)rintf(v[j].w / sc);
            qv[tid + (j << 8)] = q;
        }
    } else {
        const size_t pbase = ((size_t)(r >> 4)) << 16;  // 64 KiB per 16-row panel
        const int rsel = r & 15;
#pragma unroll
        for (int j = 0; j < 4; ++j) {
            char4 q;
            q.x = (signed char)(int)rintf(v[j].x / sc);
            q.y = (signed char)(int)rintf(v[j].y / sc);
            q.z = (signed char)(int)rintf(v[j].z / sc);
            q.w = (signed char)(int)rintf(v[j].w / sc);
            const int k = (tid + (j << 8)) << 2;          // byte col in row
            const int kt = k >> 6;
            const int lfrag = (((k & 63) >> 4) << 4) | rsel;
            *(char4*)(Wq + pbase + ((size_t)kt << 10) + (lfrag << 4) + (k & 15)) = q;
        }
    }
}

// ---------------------------------------------------------------------------
// int8 GEMM, 256x256 tile, 512 threads = 8 waves (2M x 4N), per-wave 128x64.
// A: LDS ring 4 x 16 KiB (global_load_lds staging, XOR-swizzled reads).
// B: DIRECT global->VGPR from fragment-layout w_q — 4 coalesced 1-KiB
// global_load_dwordx4 per wave per tile, double-buffered one tile ahead.
// Per-tile LDS demand drops 1400 -> ~880 cyc (A-only) < MFMA 1306 cyc:
// the r3-r7 LDS-port wall is gone and MFMA is the binding resource.
// (r8's B-direct failed on ADDRESSING — 16 lines/instr gather from
// row-major B; the fragment layout makes the same traffic coalesced.)
// Head vmcnt(0)+barrier retires everything >=1 tile (~2000 cyc) old: B(kt)
// regs (loaded at kt-1) and stage(kt+1) writes. B regs are also
// compiler-tracked (register loads), so no rule-18 hazard.
// ---------------------------------------------------------------------------
__global__ __launch_bounds__(512, 2) void gemm_i8(const int8_t* __restrict__ Aq,
                                                  const int8_t* __restrict__ Bq,
                                                  const float* __restrict__ a_scale,
                                                  const float* __restrict__ w_scale,
                                                  float* __restrict__ out) {
    extern __shared__ __align__(16) int8_t smem[];  // 4 x 16 KiB A ring

    const int K = 4096;
    const int bid = blockIdx.x;
    const int wg  = (bid & 7) * 64 + (bid >> 3);  // bijective: 512 = 8 x 64
    const int n0 = (wg & 15) * 256;
    const int m0 = (wg >> 4) * 256;

    const int tid  = threadIdx.x;
    const int lane = tid & 63;
    const int wid  = tid >> 6;
    const int wm   = wid >> 2;
    const int wn   = wid & 3;

    // A fragment read offsets in LDS (64-B rows, 16-B-chunk XOR swizzle)
    const int rsel  = lane & 15;
    const int kswz  = ((lane >> 4) << 4) ^ (((rsel >> 1) & 3) << 4);
    const int abase = (wm * 128 + rsel) * 64 + kswz;

    // B fragment-layout base: panel (n0/16 + wn*4 + nt), chunk = lane
    const int8_t* pB = Bq + (((size_t)((n0 >> 4) + (wn << 2))) << 16) + (lane << 4);

    // A staging: 512 thr x 16 B = 8 KB/issue = 128 rows; pre-swizzled source
    const int strow = tid >> 2;
    const int stswz = ((strow >> 1) & 3) << 4;
    const int stcol = ((tid & 3) << 4) ^ stswz;
    const int8_t* gA = Aq + (size_t)(m0 + strow) * K + stcol;
    const size_t rstep = (size_t)128 * K;
    const int ldsst = wid * 1024;  // + lane*16 by HW

    v4i acc[8][4] = {};
    v4i aFa[8], aFb[8], bFa[4], bFb[4];

#define STAGE(buf, kt) do {                                                          \
    int8_t* _d = smem + (buf) * 16384;                                               \
    const int8_t* _a = gA + (size_t)(kt) * 64;                                       \
    __builtin_amdgcn_global_load_lds(AS1C(_a),         AS3(_d + ldsst),        16, 0, 0); \
    __builtin_amdgcn_global_load_lds(AS1C(_a + rstep), AS3(_d + 8192 + ldsst), 16, 0, 0); \
  } while (0)

#define LOADB(NB, kt) do {                                                           \
    const int8_t* _pb = pB + ((size_t)(kt) << 10);                                   \
    NB[0] = *(const v4i*)(_pb);                                                      \
    NB[1] = *(const v4i*)(_pb + ((size_t)1 << 16));                                  \
    NB[2] = *(const v4i*)(_pb + ((size_t)2 << 16));                                  \
    NB[3] = *(const v4i*)(_pb + ((size_t)3 << 16));                                  \
  } while (0)

#define KSTEP(u, CA, CB, NA, NB, kt4) do {                                           \
    const int kt  = (kt4) + (u);                                                     \
    const int8_t* bufN = smem + (((u) + 1) & 3) * 16384;                             \
    const int ktp = (kt + 3 < 64) ? (kt + 3) : 63;                                   \
    const int ktb = (kt + 1 < 64) ? (kt + 1) : 63;                                   \
    asm volatile("s_waitcnt vmcnt(0)" ::: "memory");  /* all >=1 tile old */         \
    __builtin_amdgcn_s_barrier();                                                    \
    LOADB(NB, ktb);                                                                  \
    STAGE(((u) + 3) & 3, ktp);                                                       \
    _Pragma("unroll")                                                                \
    for (int g = 0; g < 4; ++g) {                                                    \
        NA[2*g]     = *(const v4i*)(bufN + abase + (2*g)     * 1024);                \
        NA[2*g + 1] = *(const v4i*)(bufN + abase + (2*g + 1) * 1024);                \
        __builtin_amdgcn_s_setprio(1);                                               \
        _Pragma("unroll")                                                            \
        for (int nt = 0; nt < 4; ++nt) {                                             \
            acc[2*g][nt] = __builtin_amdgcn_mfma_i32_16x16x64_i8(                    \
                CA[2*g], CB[nt], acc[2*g][nt], 0, 0, 0);                             \
            acc[2*g+1][nt] = __builtin_amdgcn_mfma_i32_16x16x64_i8(                  \
                CA[2*g+1], CB[nt], acc[2*g+1][nt], 0, 0, 0);                         \
        }                                                                            \
        __builtin_amdgcn_s_setprio(0);                                               \
    }                                                                                \
  } while (0)

    // ---- prologue: B(0) frags, stage A tiles 0..2, drain, read A(0) frags
    LOADB(bFa, 0);
    STAGE(0, 0); STAGE(1, 1); STAGE(2, 2);
    asm volatile("s_waitcnt vmcnt(0)" ::: "memory");
    __builtin_amdgcn_s_barrier();
#pragma unroll
    for (int mt = 0; mt < 8; ++mt) aFa[mt] = *(const v4i*)(smem + abase + mt * 1024);

    for (int kt4 = 0; kt4 < 64; kt4 += 4) {
        KSTEP(0, aFa, bFa, aFb, bFb, kt4);
        KSTEP(1, aFb, bFb, aFa, bFa, kt4);
        KSTEP(2, aFa, bFa, aFb, bFb, kt4);
        KSTEP(3, aFb, bFb, aFa, bFa, kt4);
    }

    // epilogue: C/D layout col = lane&15 (N), row = (lane>>4)*4 + reg (M)
    const int r0  = (lane >> 4) << 2;
    const int col = lane & 15;
#pragma unroll
    for (int mt = 0; mt < 8; ++mt) {
        const int tbase = m0 + wm * 128 + mt * 16 + r0;
        float as[4];
#pragma unroll
        for (int r = 0; r < 4; ++r) as[r] = a_scale[tbase + r];
#pragma unroll
        for (int nt = 0; nt < 4; ++nt) {
            const int o = n0 + wn * 64 + nt * 16 + col;
            const float wsc = w_scale[o];
#pragma unroll
            for (int r = 0; r < 4; ++r) {
                float v = (float)acc[mt][nt][r] * as[r] * wsc;
                out[(size_t)(tbase + r) * 4096 + o] = __half2float(__float2half_rn(v));
            }
        }
    }
#undef KSTEP
#undef LOADB
#undef STAGE
}

extern "C" void kernel_launch(void* const* d_in, const int* in_sizes, int n_in,
                              void* d_out, int out_size, void* d_ws, size_t ws_size,
                              hipStream_t stream) {
    const float* input_act = (const float*)d_in[0];  // [4,2048,4096] = [8192,4096]
    const float* weight    = (const float*)d_in[1];  // [4096,4096]
    float* out = (float*)d_out;

    const int K = 4096, O = 4096, T = 8192;

    int8_t* x_q = (int8_t*)d_ws;
    int8_t* w_q = x_q + (size_t)T * K;   // fragment layout, 16 MiB
    float* a_scale = (float*)(w_q + (size_t)O * K);
    float* w_scale = a_scale + T;

    static bool attr_done = false;
    if (!attr_done) {
        hipFuncSetAttribute(reinterpret_cast<const void*>(gemm_i8),
                            hipFuncAttributeMaxDynamicSharedMemorySize, 65536);
        attr_done = true;
    }

    quant_fused<<<T + O, 256, 0, stream>>>(input_act, weight, x_q, w_q,
                                           a_scale, w_scale);

    dim3 grid(512);  // (8192/256) x (4096/256), XCD-swizzled in-kernel
    gemm_i8<<<grid, 512, 65536, stream>>>(x_q, w_q, a_scale, w_scale, out);
}